// Round 3
// baseline (9056.494 us; speedup 1.0000x reference)
//
#include <hip/hip_runtime.h>
#include <hip/hip_fp16.h>
#include <cstdint>
#include <cstddef>

#define B_ 256
#define L_ 200
#define S_ 199
#define D_ 256
#define Q_ 20000
#define C_ 500

// ---- workspace layout (bytes, all 256-aligned) ----
#define OFF_TEPF 0u            // 200*256*4 = 204800
#define OFF_TESF 204800u       // 204800
#define OFF_CAF  409600u       // 1024
#define OFF_PPF  410624u       // 32*256*16 = 131072  (Wpf left half, f16x8 packed)
#define OFF_PSF  541696u       // 131072
#define OFF_PAF  672768u       // 131072
#define OFF_PAS  803840u       // 64*256*16 = 262144
#define OFF_PPS  1065984u      // 262144
#define OFF_PSS  1328128u      // 262144
#define OFF_PO1  1590272u      // 128*256*16 = 524288
#define OFF_PS   2114560u      // 256*199*256*4 = 52166656
#define OFF_SS   54281216u     // 52166656
// total = 106,447,872 bytes (~101.5 MB)

// TEpf[tau][d] = bpf[d] + sum_k time_embed[tau][k] * Wpf[d][256+k]; same for sf.
__global__ void te_kernel(const float* __restrict__ te,
                          const float* __restrict__ Wpf, const float* __restrict__ bpf,
                          const float* __restrict__ Wsf, const float* __restrict__ bsf,
                          float* __restrict__ TEpf, float* __restrict__ TEsf) {
  int idx = blockIdx.x * 256 + threadIdx.x;   // grid = 200 blocks -> exact
  int tau = idx >> 8, d = idx & 255;
  const float* ter = te + (tau << 8);
  const float* wp = Wpf + d * 512 + 256;
  const float* ws = Wsf + d * 512 + 256;
  float ap = 0.f, as = 0.f;
  for (int k = 0; k < 256; ++k) {
    float x = ter[k];
    ap = fmaf(x, wp[k], ap);
    as = fmaf(x, ws[k], as);
  }
  TEpf[idx] = ap + bpf[d];
  TEsf[idx] = as + bsf[d];
}

// CAF[d] = baf[d] + sum_k time_embed[1][k] * Waf[d][256+k]
__global__ void caf_kernel(const float* __restrict__ te, const float* __restrict__ Waf,
                           const float* __restrict__ baf, float* __restrict__ CAF) {
  int d = threadIdx.x;
  const float* ter = te + 256;
  const float* wa = Waf + d * 512 + 256;
  float a = 0.f;
  for (int k = 0; k < 256; ++k) a = fmaf(ter[k], wa[k], a);
  CAF[d] = a + baf[d];
}

__device__ __forceinline__ unsigned pk2(float a, float b) {
  __half2 h = __floats2half2_rn(a, b);
  return *(unsigned*)&h;
}

// Pack W[d][8k8..8k8+7] (fp32, row-major (256,fi)) -> out[k8*256+d] as 8x f16 in uint4.
__global__ void pack_kernel(const float* __restrict__ W, uint4* __restrict__ out, int fi) {
  int k8 = blockIdx.x, d = threadIdx.x;
  const float* r = W + d * fi + (k8 << 3);
  out[k8 * 256 + d] = make_uint4(pk2(r[0], r[1]), pk2(r[2], r[3]),
                                 pk2(r[4], r[5]), pk2(r[6], r[7]));
}

typedef _Float16 h2v __attribute__((ext_vector_type(2)));
union U2H { unsigned u; h2v h; __half2 hh; };

__device__ __forceinline__ float fd2(unsigned w, unsigned x, float acc) {
#if __has_builtin(__builtin_amdgcn_fdot2)
  U2H a; a.u = w; U2H b; b.u = x;
  return __builtin_amdgcn_fdot2(a.h, b.h, acc, false);
#else
  U2H a; a.u = w; U2H b; b.u = x;
  acc = fmaf(__low2float(a.hh),  __low2float(b.hh),  acc);
  acc = fmaf(__high2float(a.hh), __high2float(b.hh), acc);
  return acc;
#endif
}

__device__ __forceinline__ float dot8(uint4 w, uint4 x, float acc) {
  acc = fd2(w.x, x.x, acc);
  acc = fd2(w.y, x.y, acc);
  acc = fd2(w.z, x.z, acc);
  acc = fd2(w.w, x.w, acc);
  return acc;
}

__device__ __forceinline__ float sigf(float z) { return 1.f / (1.f + __expf(-z)); }
__device__ __forceinline__ float tanh_fast(float z) { return 1.f - 2.f / (__expf(2.f * z) + 1.f); }

// 1024 threads: thread = (d = tid&255, quarter h = tid>>8). 4-way split-K.
__global__ __launch_bounds__(1024)
void scan_kernel(const int* __restrict__ q_seq, const int* __restrict__ c_seq,
                 const int* __restrict__ a_seq,
                 const float* __restrict__ pro_embed, const float* __restrict__ skill_embed,
                 const float* __restrict__ ans_embed,
                 const float* __restrict__ ls_state,
                 const float* __restrict__ pro_state0, const float* __restrict__ skill_state0,
                 const float* __restrict__ akt_diff, const float* __restrict__ akt_change,
                 const float* __restrict__ TEpf, const float* __restrict__ TEsf,
                 const float* __restrict__ CAF,
                 const uint4* __restrict__ Ppf, const uint4* __restrict__ Psf,
                 const uint4* __restrict__ Paf,
                 const uint4* __restrict__ Pas, const uint4* __restrict__ Pps,
                 const uint4* __restrict__ Pss, const uint4* __restrict__ Po1,
                 const float* __restrict__ bas, const float* __restrict__ bps,
                 const float* __restrict__ bss, const float* __restrict__ bo1,
                 const float* __restrict__ Wo2, const float* __restrict__ bo2,
                 float* __restrict__ ps, float* __restrict__ ss,
                 float* __restrict__ out) {
  const int b = blockIdx.x;
  const int tid = threadIdx.x;
  const int d = tid & 255;
  const int h = tid >> 8;          // quarter index 0..3

  __shared__ int s_lqt[Q_];        // 80000 B: last step per question
  __shared__ int s_lct[C_];        // 2000 B
  // f32 staging / state
  __shared__ float s_lp_f[256], s_lc_f[256], s_ast_f[256];
  __shared__ float s_la_f[256], s_lp2_f[256], s_lc2_f[256];
  __shared__ float s_tge[256], s_ctge[256];
  __shared__ float s_caf[256], s_wo2[256], s_bo1[256], s_bas[256], s_bps[256], s_bss[256];
  // f16 dot inputs (16B-aligned for uint4 reads)
  __shared__ __align__(16) __half s_lp_h[256], s_lc_h[256], s_ast_h[256];
  __shared__ __align__(16) __half s_la_h[256], s_lp2_h[256], s_lc2_h[256];
  __shared__ __align__(16) __half s_pe_h[256], s_x_h[256];
  // split-K partials
  __shared__ float s_pa[1024], s_pb[1024], s_pc[1024], s_pd[1024];
  __shared__ float s_red[4];

  // ---- init ----
  for (int i = tid; i < Q_; i += 1024) s_lqt[i] = 0;
  if (tid < C_) s_lct[tid] = 0;

  float* psb = ps + (size_t)b * S_ * D_;
  float* ssb = ss + (size_t)b * S_ * D_;
  if (h == 0) {
    float a = ls_state[d];
    s_ast_f[d] = a; s_ast_h[d] = __float2half(a);
    psb[d] = pro_state0[d];      // only row 0 of the init state is ever read
    ssb[d] = skill_state0[d];
    s_caf[d] = CAF[d]; s_wo2[d] = Wo2[d];
    s_bo1[d] = bo1[d]; s_bas[d] = bas[d]; s_bps[d] = bps[d]; s_bss[d] = bss[d];
  }
  const int* qs = q_seq + b * L_;
  const int* cs = c_seq + b * L_;
  const int* as_ = a_seq + b * L_;
  const float bo2v = bo2[0];
  __syncthreads();

#pragma clang loop unroll(disable)
  for (int t = 0; t < S_; ++t) {
    const int ip = qs[t + 1];
    const int ic = cs[t + 1];
    const int ia = as_[t + 1];
    const int lp_t = s_lqt[ip];
    const int lc_t = s_lct[ic];

    // ---- staging (split across the 4 quarters) ----
    if (h == 0) {
      float lp = psb[lp_t * D_ + d];
      s_lp_f[d] = lp; s_lp_h[d] = __float2half(lp);
    } else if (h == 1) {
      float lc = ssb[lc_t * D_ + d];
      s_lc_f[d] = lc; s_lc_h[d] = __float2half(lc);
    } else if (h == 2) {
      s_tge[d] = TEpf[(t - lp_t) * D_ + d];
      float pe = pro_embed[ip * D_ + d] + skill_embed[ic * D_ + d]
               + akt_diff[ip] * akt_change[ic * D_ + d];
      s_pe_h[d] = __float2half(pe);
    } else {
      s_ctge[d] = TEsf[(t - lc_t) * D_ + d];
      float pe = pro_embed[ip * D_ + d] + skill_embed[ic * D_ + d]
               + akt_diff[ip] * akt_change[ic * D_ + d];
      s_x_h[d] = __float2half(pe + ans_embed[ia * D_ + d]);
    }
    __syncthreads();   // A

    // ---- gate phase: 3 dots K=256, quarter h covers 8 of 32 uint4 ----
    {
      const uint4* xlp = (const uint4*)s_lp_h;
      const uint4* xlc = (const uint4*)s_lc_h;
      const uint4* xas = (const uint4*)s_ast_h;
      const int j0 = h << 3;
      float a0 = 0.f, a1 = 0.f, a2 = 0.f;
#pragma unroll 8
      for (int kk = 0; kk < 8; ++kk) { int j = j0 + kk; a0 = dot8(Ppf[j * 256 + d], xlp[j], a0); }
#pragma unroll 8
      for (int kk = 0; kk < 8; ++kk) { int j = j0 + kk; a1 = dot8(Psf[j * 256 + d], xlc[j], a1); }
#pragma unroll 8
      for (int kk = 0; kk < 8; ++kk) { int j = j0 + kk; a2 = dot8(Paf[j * 256 + d], xas[j], a2); }
      s_pa[tid] = a0; s_pb[tid] = a1; s_pc[tid] = a2;
    }
    __syncthreads();   // G1

    if (h == 0) {
      float g0 = s_pa[d] + s_pa[d + 256] + s_pa[d + 512] + s_pa[d + 768];
      float g1 = s_pb[d] + s_pb[d + 256] + s_pb[d + 512] + s_pb[d + 768];
      float g2 = s_pc[d] + s_pc[d + 256] + s_pc[d + 512] + s_pc[d + 768];
      float lp2 = s_lp_f[d]  * sigf(g0 + s_tge[d]);
      float lc2 = s_lc_f[d]  * sigf(g1 + s_ctge[d]);
      float la2 = s_ast_f[d] * sigf(g2 + s_caf[d]);
      s_lp2_f[d] = lp2; s_lp2_h[d] = __float2half(lp2);
      s_lc2_f[d] = lc2; s_lc2_h[d] = __float2half(lc2);
      s_la_f[d]  = la2; s_la_h[d]  = __float2half(la2);
      if (d == 0) { s_lqt[ip] = t; s_lct[ic] = t; }
    }
    __syncthreads();   // G2

    // ---- phase B: Wo1 (K=1024) + Was/Wps/Wss (K=512), fused per x-segment ----
    {
      const uint4* xla = (const uint4*)s_la_h;
      const uint4* xlp = (const uint4*)s_lp2_h;
      const uint4* xlc = (const uint4*)s_lc2_h;
      const uint4* xpe = (const uint4*)s_pe_h;
      const uint4* xx  = (const uint4*)s_x_h;
      const int j0 = h << 3;
      float accO = 0.f, accA = 0.f, accP = 0.f, accC = 0.f;
#pragma unroll 4
      for (int kk = 0; kk < 8; ++kk) { int j = j0 + kk; uint4 v = xla[j];
        accO = dot8(Po1[j * 256 + d], v, accO);
        accA = dot8(Pas[j * 256 + d], v, accA); }
#pragma unroll 4
      for (int kk = 0; kk < 8; ++kk) { int j = j0 + kk; uint4 v = xlp[j];
        accO = dot8(Po1[(32 + j) * 256 + d], v, accO);
        accP = dot8(Pps[j * 256 + d], v, accP); }
#pragma unroll 4
      for (int kk = 0; kk < 8; ++kk) { int j = j0 + kk; uint4 v = xlc[j];
        accO = dot8(Po1[(64 + j) * 256 + d], v, accO);
        accC = dot8(Pss[j * 256 + d], v, accC); }
#pragma unroll 8
      for (int kk = 0; kk < 8; ++kk) { int j = j0 + kk;
        accO = dot8(Po1[(96 + j) * 256 + d], xpe[j], accO); }
#pragma unroll 4
      for (int kk = 0; kk < 8; ++kk) { int j = j0 + kk; uint4 v = xx[j];
        accA = dot8(Pas[(32 + j) * 256 + d], v, accA);
        accP = dot8(Pps[(32 + j) * 256 + d], v, accP);
        accC = dot8(Pss[(32 + j) * 256 + d], v, accC); }
      s_pa[tid] = accO; s_pb[tid] = accA; s_pc[tid] = accP; s_pd[tid] = accC;
    }
    __syncthreads();   // P1

    if (h == 0) {
      float accO = s_pa[d] + s_pa[d + 256] + s_pa[d + 512] + s_pa[d + 768];
      float accA = s_pb[d] + s_pb[d + 256] + s_pb[d + 512] + s_pb[d + 768];
      float accP = s_pc[d] + s_pc[d + 256] + s_pc[d + 512] + s_pc[d + 768];
      float accC = s_pd[d] + s_pd[d + 256] + s_pd[d + 512] + s_pd[d + 768];
      float o1 = fmaxf(accO + s_bo1[d], 0.f);
      float r = o1 * s_wo2[d];
#pragma unroll
      for (int off = 32; off; off >>= 1) r += __shfl_down(r, off);
      float a_new = s_la_f[d]  + tanh_fast(accA + s_bas[d]);
      float p_new = s_lp2_f[d] + tanh_fast(accP + s_bps[d]);
      float c_new = s_lc2_f[d] + tanh_fast(accC + s_bss[d]);
      s_ast_f[d] = a_new; s_ast_h[d] = __float2half(a_new);
      psb[t * D_ + d] = p_new;
      ssb[t * D_ + d] = c_new;
      if ((d & 63) == 0) s_red[d >> 6] = r;
    }
    __syncthreads();   // P2
    if (tid == 0) {
      float z = s_red[0] + s_red[1] + s_red[2] + s_red[3] + bo2v;
      out[b * S_ + t] = 1.f / (1.f + __expf(-z));
    }
  }
}

extern "C" void kernel_launch(void* const* d_in, const int* in_sizes, int n_in,
                              void* d_out, int out_size, void* d_ws, size_t ws_size,
                              hipStream_t stream) {
  const int*   q_seq        = (const int*)d_in[0];
  const int*   c_seq        = (const int*)d_in[1];
  const int*   a_seq        = (const int*)d_in[2];
  const float* pro_embed    = (const float*)d_in[3];
  const float* skill_embed  = (const float*)d_in[4];
  const float* ans_embed    = (const float*)d_in[5];
  const float* time_embed   = (const float*)d_in[6];
  const float* ls_state     = (const float*)d_in[7];
  const float* pro_state0   = (const float*)d_in[8];
  const float* skill_state0 = (const float*)d_in[9];
  const float* akt_diff     = (const float*)d_in[10];
  const float* akt_change   = (const float*)d_in[11];
  const float* Wpf = (const float*)d_in[12]; const float* bpf = (const float*)d_in[13];
  const float* Wps = (const float*)d_in[14]; const float* bps = (const float*)d_in[15];
  const float* Wsf = (const float*)d_in[16]; const float* bsf = (const float*)d_in[17];
  const float* Wss = (const float*)d_in[18]; const float* bss = (const float*)d_in[19];
  const float* Waf = (const float*)d_in[20]; const float* baf = (const float*)d_in[21];
  const float* Was = (const float*)d_in[22]; const float* bas = (const float*)d_in[23];
  const float* Wo1 = (const float*)d_in[24]; const float* bo1 = (const float*)d_in[25];
  const float* Wo2 = (const float*)d_in[26]; const float* bo2 = (const float*)d_in[27];

  char* ws = (char*)d_ws;
  float* TEpf = (float*)(ws + OFF_TEPF);
  float* TEsf = (float*)(ws + OFF_TESF);
  float* CAF  = (float*)(ws + OFF_CAF);
  uint4* Ppf  = (uint4*)(ws + OFF_PPF);
  uint4* Psf  = (uint4*)(ws + OFF_PSF);
  uint4* Paf  = (uint4*)(ws + OFF_PAF);
  uint4* Pas  = (uint4*)(ws + OFF_PAS);
  uint4* Pps  = (uint4*)(ws + OFF_PPS);
  uint4* Pss  = (uint4*)(ws + OFF_PSS);
  uint4* Po1  = (uint4*)(ws + OFF_PO1);
  float* ps   = (float*)(ws + OFF_PS);
  float* ssb  = (float*)(ws + OFF_SS);
  float* out  = (float*)d_out;

  te_kernel<<<200, 256, 0, stream>>>(time_embed, Wpf, bpf, Wsf, bsf, TEpf, TEsf);
  caf_kernel<<<1, 256, 0, stream>>>(time_embed, Waf, baf, CAF);

  // gate matrices: left half only (state part), K=256 -> 32 k8-blocks
  pack_kernel<<<32, 256, 0, stream>>>(Wpf, Ppf, 512);
  pack_kernel<<<32, 256, 0, stream>>>(Wsf, Psf, 512);
  pack_kernel<<<32, 256, 0, stream>>>(Waf, Paf, 512);
  // full K=512 update matrices
  pack_kernel<<<64, 256, 0, stream>>>(Was, Pas, 512);
  pack_kernel<<<64, 256, 0, stream>>>(Wps, Pps, 512);
  pack_kernel<<<64, 256, 0, stream>>>(Wss, Pss, 512);
  // Wo1: K=1024
  pack_kernel<<<128, 256, 0, stream>>>(Wo1, Po1, 1024);

  scan_kernel<<<B_, 1024, 0, stream>>>(q_seq, c_seq, a_seq,
                                       pro_embed, skill_embed, ans_embed,
                                       ls_state, pro_state0, skill_state0,
                                       akt_diff, akt_change,
                                       TEpf, TEsf, CAF,
                                       Ppf, Psf, Paf, Pas, Pps, Pss, Po1,
                                       bas, bps, bss, bo1, Wo2, bo2,
                                       ps, ssb, out);
}